// Round 15
// baseline (135.318 us; speedup 1.0000x reference)
//
#include <hip/hip_runtime.h>

// CRS rate-and-state model. R -> et*R/(1+c*R) is a Mobius map [[a,0],[c,1]];
// maps compose associatively -> whole T=4096 row is ONE two-level scan.
// R15: NO LDS BOUNCE. Alignment comes from the WORK ASSIGNMENT, not LDS:
// thread t owns steps [sig+8t, sig+8t+8) where sig = (4-(g0&3))&3 makes
// g0+sig 16B-aligned -> each thread's 8 results are a 16B-aligned wave-
// contiguous span -> direct nt f4 stores from registers. Wave spans tile the
// row contiguously so all interior 64B lines are fully written (no RMW; only
// ~1 boundary line per row = ~1MB). sig-head (<=3 steps): serial closed-form
// by tid 0, folded into the carry via sH broadcast. Ragged tail (8-sig
// steps): serial closed-form by tid 511 (participates in scans as identity).
// Removes per row: 33KB LDS (occupancy uncapped), 32 DS ops + ~60 SIDX/addr
// VALU per thread, 1.7M bank-conflict cycles, 1 barrier. Rationale: R11
// traffic -12% -> time -1.5% (not BW-bound); R12-R14 register pipelining
// defeated by compiler 3x (VGPR 40 tell); residual = VALU/LDS leg.
// Keeps: nt stores (R9 L3 win), lgkm-only barriers (no vmcnt(0) drain of
// in-flight nt stores), plain compiler-managed loads (no asm games).

#define C_TNSR  0.001f
#define C_TSSR  0.002f
#define C_SIGMA 50.0f
#define C_BIOT  0.3f
#define C_R0    0.0001f
#define C_N0    0.0001f

constexpr int B = 8192;
constexpr int T = 4096;
constexpr int STEPS = 8;           // per thread
constexpr int NTHR  = 512;         // threads per block = one row
constexpr int WAVES = NTHR / 64;   // 8

typedef float f4  __attribute__((ext_vector_type(4)));
typedef float f4u __attribute__((ext_vector_type(4), aligned(4)));  // 4B-aligned load

// one exact recurrence step (used by head/tail serial edge workers)
#define STEP_EDGE(pp, dd, tt, Rv, n_out) do {                         \
    float sd_   = C_TSSR - mu * (C_TNSR - (dd));                      \
    float asig_ = fmaf(-rcB, (pp), rcS);                              \
    float e_    = __expf(__fdividef(sd_ * (tt), asig_));              \
    float c_    = __fdividef(eta * (e_ - 1.0f), sd_);                 \
    float den_  = fmaf(c_, (Rv), 1.0f);                               \
    (n_out)     = (asig_ * rf) * __logf(den_);                        \
    (Rv)        = __fdividef((Rv) * e_, den_);                        \
} while (0)

// workgroup barrier WITHOUT the compiler's vmcnt(0) drain: we only need LDS
// ordering, and draining would stall on our in-flight nt stores.
__device__ __forceinline__ void barrier_lgkm() {
    asm volatile("s_waitcnt lgkmcnt(0)\n\ts_barrier" ::: "memory");
}

__global__ __launch_bounds__(NTHR, 4)
void crs_row_kernel(const float* __restrict__ params,
                    const float* __restrict__ p,
                    const float* __restrict__ dpdt,
                    const float* __restrict__ dtv,
                    float* __restrict__ Rt,
                    float* __restrict__ Nt)
{
    __shared__ float sA[WAVES], sC[WAVES], sS[WAVES], sH[2];

    const int tid  = threadIdx.x;
    const int lane = tid & 63;
    const int wid  = tid >> 6;
    const int b    = blockIdx.x;

    const float mu  = params[b * 3 + 0];
    const float rc  = params[b * 3 + 1];
    const float rf  = params[b * 3 + 2];
    const float eta = 1.0f / rf;
    const float rcS = rc * C_SIGMA;
    const float rcB = rc * C_BIOT;

    const float* __restrict__ prow = p    + (size_t)b * T;
    const float* __restrict__ drow = dpdt + (size_t)b * T;
    const float* __restrict__ trow = dtv  + (size_t)b * T;

    const size_t g0  = (size_t)b * (T + 1) + 1;        // dword index of step-0 output
    const int    sig = (int)((4 - (g0 & 3)) & 3);      // shift so g0+sig is 16B-aligned
    const bool   tw  = (tid == NTHR - 1);              // tail worker

    const int seg0 = sig + STEPS * tid;                // this thread's first step
    const int lb   = tw ? (T - 8) : seg0;              // tail worker: aligned, in-bounds

    // ---- loads: 8 floats per stream (4B-aligned 16B loads, wave-contiguous) ----
    f4u pv0 = *(const f4u*)(prow + lb);
    f4u pv1 = *(const f4u*)(prow + lb + 4);
    f4u dv0 = *(const f4u*)(drow + lb);
    f4u dv1 = *(const f4u*)(drow + lb + 4);
    f4u tv0 = *(const f4u*)(trow + lb);
    f4u tv1 = *(const f4u*)(trow + lb + 4);

    // ---- head worker (tid 0): boundary + steps [0, sig), carry via sH ----
    if (tid == 0) {
        float Rh = C_R0, Nh = 0.0f;
        __builtin_nontemporal_store(C_R0, Rt + g0 - 1);
        __builtin_nontemporal_store(C_N0, Nt + g0 - 1);
        if (sig > 0) {
            f4 hp = *(const f4*)(prow);   // aligned head loads (<=4 floats needed)
            f4 hd = *(const f4*)(drow);
            f4 ht = *(const f4*)(trow);
#pragma unroll
            for (int j = 0; j < 3; ++j) {
                if (j < sig) {
                    float n;
                    STEP_EDGE(hp[j], hd[j], ht[j], Rh, n);
                    Nh += n;
                    __builtin_nontemporal_store(Rh, Rt + g0 + j);
                    __builtin_nontemporal_store(C_N0 + Nh, Nt + g0 + j);
                }
            }
        }
        sH[0] = Rh;
        sH[1] = Nh;
    }

    // ---- phase 1: per-thread inclusive Mobius prefixes over its 8 steps ----
    float Aj[STEPS], Cj[STEPS], kk[STEPS];
    float A = 1.0f, C = 0.0f;
#pragma unroll
    for (int j = 0; j < STEPS; ++j) {
        float pp = (j < 4) ? pv0[j] : pv1[j - 4];
        float dd = (j < 4) ? dv0[j] : dv1[j - 4];
        float tt = (j < 4) ? tv0[j] : tv1[j - 4];
        float sd   = C_TSSR - mu * (C_TNSR - dd);
        float asig = fmaf(-rcB, pp, rcS);
        float e    = __expf(__fdividef(sd * tt, asig));
        float c    = __fdividef(eta * (e - 1.0f), sd);
        kk[j] = asig * rf;               // asig/eta
        C = fmaf(c, A, C);               // compose step j after (A,C)
        A = A * e;
        Aj[j] = A;
        Cj[j] = C;
    }
    // tail worker contributes IDENTITY to the scan (its slots duplicate
    // thread 510's tail elements; real tail handled serially at the end)
    A = tw ? 1.0f : A;
    C = tw ? 0.0f : C;

    // ---- phase 2a: wave-inclusive scan of (A,C) ----
#pragma unroll
    for (int o = 1; o < 64; o <<= 1) {
        float Ap = __shfl_up(A, (unsigned)o, 64);
        float Cp = __shfl_up(C, (unsigned)o, 64);
        if (lane >= o) { C = fmaf(C, Ap, Cp); A = A * Ap; }
    }
    float Ae = __shfl_up(A, 1u, 64);
    float Ce = __shfl_up(C, 1u, 64);
    if (lane == 0) { Ae = 1.0f; Ce = 0.0f; }

    // ---- phase 2b: cross-wave composition via LDS ----
    if (lane == 63) { sA[wid] = A; sC[wid] = C; }
    barrier_lgkm();                                    // bar 1
    float PA = 1.0f, PC = 0.0f;
#pragma unroll
    for (int w = 0; w < WAVES - 1; ++w) {
        if (w < wid) { PC = fmaf(sC[w], PA, PC); PA = sA[w] * PA; }
    }
    const float Rh = sH[0];                            // R entering the body
    const float Nh = sH[1];
    float EA = Ae * PA;
    float EC = fmaf(Ce, PA, PC);
    float Rt_ = __fdividef(EA * Rh, fmaf(EC, Rh, 1.0f));  // R entering segment

    // ---- phase 3: closed-form R outputs (direct aligned nt f4 stores) ----
    float nn[STEPS];
    float ns = 0.0f;
    float rlPrev = 1.0f;
    f4 rb0, rb1;
#pragma unroll
    for (int j = 0; j < STEPS; ++j) {
        float L   = fmaf(Cj[j], Rt_, 1.0f);
        float rlj = __fdividef(1.0f, L);
        float Rv  = (Aj[j] * Rt_) * rlj;
        if (j < 4) rb0[j] = Rv; else rb1[j - 4] = Rv;
        float den = L * rlPrev;                        // == 1 + c_j*R_{j-1}
        ns += kk[j] * __logf(den);
        nn[j] = ns;
        rlPrev = rlj;
    }
    if (!tw) {
        __builtin_nontemporal_store(rb0, (f4*)(Rt + g0 + seg0));
        __builtin_nontemporal_store(rb1, (f4*)(Rt + g0 + seg0 + 4));
    }
    ns = tw ? 0.0f : ns;                               // identity in N scan too

    // ---- phase 4: two-level prefix sum of per-thread N totals ----
    float S = ns;
#pragma unroll
    for (int o = 1; o < 64; o <<= 1) {
        float Sp = __shfl_up(S, (unsigned)o, 64);
        if (lane >= o) S += Sp;
    }
    if (lane == 63) sS[wid] = S;
    barrier_lgkm();                                    // bar 2
    float PS = C_N0 + Nh;
#pragma unroll
    for (int w = 0; w < WAVES - 1; ++w) {
        if (w < wid) PS += sS[w];
    }
    float base = PS + (S - ns);

    if (!tw) {
        f4 nb0, nb1;
#pragma unroll
        for (int c = 0; c < 4; ++c) { nb0[c] = base + nn[c]; nb1[c] = base + nn[4 + c]; }
        __builtin_nontemporal_store(nb0, (f4*)(Nt + g0 + seg0));
        __builtin_nontemporal_store(nb1, (f4*)(Nt + g0 + seg0 + 4));
    } else {
        // ---- tail worker: steps [sig+4088, 4096) serially, exact recurrence ----
        float Rv = Rt_;            // state entering the tail (all body composed)
        float Ncum = base;         // N through last body step
#pragma unroll
        for (int j = 0; j < STEPS; ++j) {
            if (j >= sig) {        // slot j <-> element (T-8)+j
                float pp = (j < 4) ? pv0[j] : pv1[j - 4];
                float dd = (j < 4) ? dv0[j] : dv1[j - 4];
                float tt = (j < 4) ? tv0[j] : tv1[j - 4];
                float n;
                STEP_EDGE(pp, dd, tt, Rv, n);
                Ncum += n;
                __builtin_nontemporal_store(Rv,   Rt + g0 + (T - 8) + j);
                __builtin_nontemporal_store(Ncum, Nt + g0 + (T - 8) + j);
            }
        }
    }
}

extern "C" void kernel_launch(void* const* d_in, const int* in_sizes, int n_in,
                              void* d_out, int out_size, void* d_ws, size_t ws_size,
                              hipStream_t stream)
{
    const float* params = (const float*)d_in[0];
    const float* p      = (const float*)d_in[1];
    const float* dpdt   = (const float*)d_in[2];
    const float* dtv    = (const float*)d_in[3];

    float* Rt = (float*)d_out;                       // B*(T+1)
    float* Nt = (float*)d_out + (size_t)B * (T + 1); // B*(T+1)

    crs_row_kernel<<<B, NTHR, 0, stream>>>(params, p, dpdt, dtv, Rt, Nt);
}

// Round 16
// 125.694 us; speedup vs baseline: 1.0766x; 1.0766x over previous
//
#include <hip/hip_runtime.h>

// CRS rate-and-state model. R -> et*R/(1+c*R) is a Mobius map [[a,0],[c,1]];
// maps compose associatively -> whole T=4096 row is ONE two-level scan.
// R16 = R11 (best: 126us; 512thr, dual skewed LDS bounce, aligned nt stores)
// + three trims:
//  1. log2-telescope: n_j = (asig*rf*ln2)*(log2 L_j - log2 L_{j-1}) — kills
//     den-mul and the rlPrev serial chain (8 logs now independent).
//  2. R-store (VMEM pipe) issued BEFORE N-bounce writes (DS pipe): the two
//     pipes overlap; barriers are lgkm-only so no vmcnt(0) drain stalls on
//     the in-flight nt R-stores.
//  3. launch_bounds(512,8): VGPR cap 64 (usage 28-40, no spill) to pack the
//     full 4 blocks/CU (R11 measured 71%).
// Keeps: dual LDS bounce for per-WAVE-INSTRUCTION lane-contiguity (R10: nt
// thread-contiguous = 3.2x WRITE amp; R15: 32B-stride lanes = +31MB), dword
// skew (2-way banks = free), per-row phase shift -> 64B-aligned f4 nt stores
// (R6 RMW win), nt stores for L3 input retention (R9 win).

#define C_TNSR  0.001f
#define C_TSSR  0.002f
#define C_SIGMA 50.0f
#define C_BIOT  0.3f
#define C_R0    0.0001f
#define C_N0    0.0001f
#define LN2F    0.69314718056f

constexpr int B = 8192;
constexpr int T = 4096;
constexpr int STEPS = 8;           // per thread
constexpr int NTHR  = 512;         // threads per block = one row
constexpr int WAVES = NTHR / 64;   // 8

typedef float f4 __attribute__((ext_vector_type(4)));

__device__ __forceinline__ int SIDX(int m) { return m + (m >> 5); }

// workgroup barrier WITHOUT the compiler's vmcnt(0) drain: LDS ordering only;
// draining would stall on our in-flight nt stores.
__device__ __forceinline__ void barrier_lgkm() {
    asm volatile("s_waitcnt lgkmcnt(0)\n\ts_barrier" ::: "memory");
}

__global__ __launch_bounds__(NTHR, 8)
void crs_row_kernel(const float* __restrict__ params,
                    const float* __restrict__ p,
                    const float* __restrict__ dpdt,
                    const float* __restrict__ dtv,
                    float* __restrict__ Rt,
                    float* __restrict__ Nt)
{
    __shared__ float lsR[T + T / 32];   // 16.5 KB, skew-indexed
    __shared__ float lsN[T + T / 32];
    __shared__ float sA[WAVES], sC[WAVES], sS[WAVES];

    const int tid  = threadIdx.x;
    const int lane = tid & 63;
    const int wid  = tid >> 6;
    const int b    = blockIdx.x;

    const float mu  = params[b * 3 + 0];
    const float rc  = params[b * 3 + 1];
    const float rf  = params[b * 3 + 2];
    const float eta = 1.0f / rf;
    const float rcS = rc * C_SIGMA;
    const float rcB = rc * C_BIOT;
    const float sdB = C_TSSR - mu * C_TNSR;    // sd = fma(mu, dpdt, sdB)
    const float rfln2 = rf * LN2F;             // kln = asig * rfln2

    const int seg = tid * STEPS;
    const float* __restrict__ prow = p    + (size_t)b * T + seg;
    const float* __restrict__ drow = dpdt + (size_t)b * T + seg;
    const float* __restrict__ trow = dtv  + (size_t)b * T + seg;

    // ---- load this thread's 8 steps (32B/thread dwordx4, dense) ----
    f4 pv0 = *(const f4*)(prow);
    f4 pv1 = *(const f4*)(prow + 4);
    f4 dv0 = *(const f4*)(drow);
    f4 dv1 = *(const f4*)(drow + 4);
    f4 tv0 = *(const f4*)(trow);
    f4 tv1 = *(const f4*)(trow + 4);

    // ---- phase 1: per-thread inclusive Mobius prefixes ----
    float Aj[STEPS], Cj[STEPS], kln[STEPS];
    float A = 1.0f, C = 0.0f;
#pragma unroll
    for (int j = 0; j < STEPS; ++j) {
        float pp = (j < 4) ? pv0[j] : pv1[j - 4];
        float dd = (j < 4) ? dv0[j] : dv1[j - 4];
        float tt = (j < 4) ? tv0[j] : tv1[j - 4];
        float sd   = fmaf(mu, dd, sdB);
        float asig = fmaf(-rcB, pp, rcS);
        float e    = __expf(__fdividef(sd * tt, asig));
        float c    = __fdividef(eta * (e - 1.0f), sd);
        kln[j] = asig * rfln2;           // (asig/eta)*ln2
        C = fmaf(c, A, C);               // compose step j after (A,C)
        A = A * e;
        Aj[j] = A;
        Cj[j] = C;
    }

    // ---- phase 2a: wave-inclusive scan of (A,C) ----
#pragma unroll
    for (int o = 1; o < 64; o <<= 1) {
        float Ap = __shfl_up(A, (unsigned)o, 64);
        float Cp = __shfl_up(C, (unsigned)o, 64);
        if (lane >= o) { C = fmaf(C, Ap, Cp); A = A * Ap; }
    }
    float Ae = __shfl_up(A, 1u, 64);
    float Ce = __shfl_up(C, 1u, 64);
    if (lane == 0) { Ae = 1.0f; Ce = 0.0f; }

    // ---- phase 2b: cross-wave composition via LDS ----
    if (lane == 63) { sA[wid] = A; sC[wid] = C; }
    barrier_lgkm();                                    // bar 1
    float PA = 1.0f, PC = 0.0f;
#pragma unroll
    for (int w = 0; w < WAVES - 1; ++w) {
        if (w < wid) { PC = fmaf(sC[w], PA, PC); PA = sA[w] * PA; }
    }
    float EA = Ae * PA;
    float EC = fmaf(Ce, PA, PC);
    float Rt_ = __fdividef(EA * C_R0, fmaf(EC, C_R0, 1.0f));   // R entering segment

    // ---- phase 3: closed-form outputs; N via log2 telescope ----
    // L_j = 1 + Cj*R~ ;  R_j = Aj*R~/L_j ;  n_j = kln_j*(lg_j - lg_{j-1}),
    // lg_j = log2(L_j), lg_{-1} = 0. All logs/rcps independent.
    float nn[STEPS];
    float ns = 0.0f;
    float lgPrev = 0.0f;
#pragma unroll
    for (int j = 0; j < STEPS; ++j) {
        float L   = fmaf(Cj[j], Rt_, 1.0f);
        float rlj = __fdividef(1.0f, L);
        lsR[SIDX(seg + j)] = (Aj[j] * Rt_) * rlj;
        float lg = __log2f(L);
        ns += kln[j] * (lg - lgPrev);
        nn[j] = ns;
        lgPrev = lg;
    }

    // ---- phase 4a: wave prefix sum of per-thread N totals (shuffles only) ----
    float S = ns;
#pragma unroll
    for (int o = 1; o < 64; o <<= 1) {
        float Sp = __shfl_up(S, (unsigned)o, 64);
        if (lane >= o) S += Sp;
    }
    if (lane == 63) sS[wid] = S;
    barrier_lgkm();                                    // bar 2: lsR + sS ready

    // ---- store-stage geometry ----
    const size_t g0 = (size_t)b * (T + 1) + 1;         // dword index of step 0
    const int s  = (int)((16 - (g0 & 15)) & 15);       // shift to 64B boundary
    const int tl = (T - s) & 3;                        // tail dwords
    const int bodyEnd = T - tl;

    // ---- R store stage FIRST (VMEM pipe; overlaps the N work below) ----
    if (tid == 0) {
        __builtin_nontemporal_store(C_R0, Rt + g0 - 1);
        __builtin_nontemporal_store(C_N0, Nt + g0 - 1);
    }
    if (tid < s)  __builtin_nontemporal_store(lsR[SIDX(tid)], Rt + g0 + tid);
    if (tid < tl) { int m = bodyEnd + tid;
                    __builtin_nontemporal_store(lsR[SIDX(m)], Rt + g0 + m); }
#pragma unroll
    for (int q = 0; q < 2; ++q) {                      // body: 64B-aligned f4
        int m0 = s + q * 2048 + tid * 4;
        if (m0 + 4 <= bodyEnd) {
            f4 r;
#pragma unroll
            for (int c = 0; c < 4; ++c) r[c] = lsR[SIDX(m0 + c)];
            __builtin_nontemporal_store(r, (f4*)(Rt + g0 + m0));
        }
    }

    // ---- phase 4b: cross-wave N base + bounce N (DS pipe, concurrent) ----
    float PS = C_N0;
#pragma unroll
    for (int w = 0; w < WAVES - 1; ++w) {
        if (w < wid) PS += sS[w];
    }
    float base = PS + (S - ns);
#pragma unroll
    for (int j = 0; j < STEPS; ++j)
        lsN[SIDX(seg + j)] = base + nn[j];

    barrier_lgkm();                                    // bar 3: N in LDS

    // ---- N store stage ----
    if (tid < s)  __builtin_nontemporal_store(lsN[SIDX(tid)], Nt + g0 + tid);
    if (tid < tl) { int m = bodyEnd + tid;
                    __builtin_nontemporal_store(lsN[SIDX(m)], Nt + g0 + m); }
#pragma unroll
    for (int q = 0; q < 2; ++q) {
        int m0 = s + q * 2048 + tid * 4;
        if (m0 + 4 <= bodyEnd) {
            f4 n;
#pragma unroll
            for (int c = 0; c < 4; ++c) n[c] = lsN[SIDX(m0 + c)];
            __builtin_nontemporal_store(n, (f4*)(Nt + g0 + m0));
        }
    }
}

extern "C" void kernel_launch(void* const* d_in, const int* in_sizes, int n_in,
                              void* d_out, int out_size, void* d_ws, size_t ws_size,
                              hipStream_t stream)
{
    const float* params = (const float*)d_in[0];
    const float* p      = (const float*)d_in[1];
    const float* dpdt   = (const float*)d_in[2];
    const float* dtv    = (const float*)d_in[3];

    float* Rt = (float*)d_out;                       // B*(T+1)
    float* Nt = (float*)d_out + (size_t)B * (T + 1); // B*(T+1)

    crs_row_kernel<<<B, NTHR, 0, stream>>>(params, p, dpdt, dtv, Rt, Nt);
}